// Round 16
// baseline (370.565 us; speedup 1.0000x reference)
//
#include <hip/hip_runtime.h>
#include <hip/hip_bf16.h>
#include <hip/hip_fp16.h>

#define N_TOK 524288
#define DM 256
#define HID 512
#define OUTD 32
#define NTYPE 4
#define TBM 32                     // rows per (1-wave) block
#define MT 2
#define HC 32
#define NCHUNK (HID / HC)          // 16
#define NBLK 512                   // partition blocks; N_TOK = NBLK * 1024
#define GX1D (N_TOK / TBM + NTYPE) // exact tiles + per-type ceil slack

typedef _Float16 half8 __attribute__((ext_vector_type(8)));
typedef float f32x4 __attribute__((ext_vector_type(4)));

#define AS1 __attribute__((address_space(1)))
#define AS3 __attribute__((address_space(3)))

// ---------------- deterministic atomic-free partition ----------------

__global__ void count_kernel(const int* __restrict__ types, int* __restrict__ bc) {
    __shared__ int c[NTYPE];
    int tid = threadIdx.x;
    if (tid < NTYPE) c[tid] = 0;
    __syncthreads();
    int b = blockIdx.x;
    int lane = tid & 63;
    #pragma unroll
    for (int j = 0; j < 4; ++j) {
        int t = types[b * 1024 + j * 256 + tid];
        #pragma unroll
        for (int tt = 0; tt < NTYPE; ++tt) {
            unsigned long long mask = __ballot(t == tt);
            if (lane == 0) atomicAdd(&c[tt], __popcll(mask));
        }
    }
    __syncthreads();
    if (tid < NTYPE) bc[tid * NBLK + b] = c[tid];
}

// meta: [0..3] counts, [4..7] row offsets, [8..11] tile offsets (TBM), [12] total
__global__ void scan_blocks_kernel(const int* __restrict__ bc,
                                   int* __restrict__ bb,
                                   int* __restrict__ meta) {
    __shared__ int totals[NTYPE];
    __shared__ int typeoff[NTYPE];
    int wave = threadIdx.x >> 6, lane = threadIdx.x & 63;
    int excl[NBLK / 64];
    int running = 0;
    #pragma unroll
    for (int it = 0; it < NBLK / 64; ++it) {
        int v = bc[wave * NBLK + it * 64 + lane];
        int s = v;
        #pragma unroll
        for (int d = 1; d < 64; d <<= 1) {
            int u = __shfl_up(s, d);
            if (lane >= d) s += u;
        }
        excl[it] = running + s - v;
        running += __shfl(s, 63);
    }
    if (lane == 0) totals[wave] = running;
    __syncthreads();
    if (threadIdx.x == 0) {
        int off = 0, toff = 0;
        for (int tt = 0; tt < NTYPE; ++tt) {
            typeoff[tt] = off;
            meta[tt] = totals[tt];
            meta[4 + tt] = off;
            meta[8 + tt] = toff;
            off += totals[tt];
            toff += (totals[tt] + TBM - 1) / TBM;
        }
        meta[12] = toff;
    }
    __syncthreads();
    #pragma unroll
    for (int it = 0; it < NBLK / 64; ++it)
        bb[wave * NBLK + it * 64 + lane] = typeoff[wave] + excl[it];
}

__global__ void scatter2_kernel(const int* __restrict__ types,
                                const int* __restrict__ bb,
                                int* __restrict__ idx) {
    __shared__ int base[NTYPE];
    __shared__ int wcnt[4][NTYPE];
    int b = blockIdx.x;
    int tid = threadIdx.x, wave = tid >> 6, lane = tid & 63;
    if (tid < NTYPE) base[tid] = bb[tid * NBLK + b];
    #pragma unroll
    for (int j = 0; j < 4; ++j) {
        __syncthreads();
        int i = b * 1024 + j * 256 + tid;
        int t = types[i];
        int rank = 0;
        #pragma unroll
        for (int tt = 0; tt < NTYPE; ++tt) {
            unsigned long long mask = __ballot(t == tt);
            if (t == tt) rank = __popcll(mask & ((1ull << lane) - 1ull));
            if (lane == 0) wcnt[wave][tt] = __popcll(mask);
        }
        __syncthreads();
        int pre = 0;
        for (int w = 0; w < wave; ++w) pre += wcnt[w][t];
        idx[base[t] + pre + rank] = i;
        __syncthreads();
        if (tid < NTYPE) {
            int tot = 0;
            #pragma unroll
            for (int w = 0; w < 4; ++w) tot += wcnt[w][tid];
            base[tid] += tot;
        }
    }
}

// ---------------- weight prep ----------------
// W1F: FRAG-MAJOR global layout, read directly by each wave (no LDS, no
// barriers): W1F[t][hc][kk][nt][lane][8 f16], lane=(lg<<4)|l15, so each
// (kk,nt) fragment load is 64 lanes x 16B fully coalesced (1 KB).
//   h = hc*32 + nt*16 + l15 ; d = kk*32 + lg*8 + j
// W2T: [t][o][p] f16, hidden dim permuted per 32-chunk so swapped-GEMM1's
// register layout (h = nt*16+lg*4+j) equals the K=32 B-operand slot order
// (p = lg*8+j): p -> h1 = j<4 ? lg*4+j : 16+lg*4+(j-4)

__global__ void wprep_kernel(const float* __restrict__ W1, const float* __restrict__ W2,
                             _Float16* __restrict__ W1F, _Float16* __restrict__ W2T) {
    int i = blockIdx.x * blockDim.x + threadIdx.x;
    if (i < NTYPE * HID * DM) {
        int t = i / (HID * DM);
        int slot = i - t * (HID * DM);
        int hc = slot >> 13;          // 8192 elems per chunk
        int rem = slot & 8191;
        int kk = rem >> 10;
        int rem2 = rem & 1023;
        int nt = rem2 >> 9;
        int rem3 = rem2 & 511;
        int lane = rem3 >> 3;
        int j = rem3 & 7;
        int lg = lane >> 4, l15 = lane & 15;
        int h = hc * HC + nt * 16 + l15;
        int d = kk * 32 + lg * 8 + j;
        W1F[i] = (_Float16)W1[(t * DM + d) * HID + h];
    }
    if (i < NTYPE * OUTD * HID) {
        int t = i / (OUTD * HID);
        int r = i - t * (OUTD * HID);
        int o = r / HID;
        int pg = r - o * HID;
        int hc = pg >> 5;
        int p = pg & 31;
        int lg = p >> 3, j = p & 7;
        int h1 = (j < 4) ? (lg * 4 + j) : (16 + lg * 4 + (j - 4));
        int h = hc * HC + h1;
        W2T[i] = (_Float16)W2[(t * HID + h) * OUTD + o];
    }
}

// ---------------- fused MLP: 1-wave blocks, ZERO barriers ----------------
// Diagnosis (R14 counters): MfmaUtil/VALUBusy/Occ all ~21% -- pipes serialized
// by barrier lockstep, not saturated. This version removes ALL inter-wave
// coupling: each 64-thread block owns 32 rows; W1 fragments are read straight
// from L1/L2 via the frag-major W1F layout (coalesced 1 KB loads); bias from
// global per chunk; LDS = 8 KB wave-private gather scratch only. 16
// independent waves/CU mix gather/GEMM phases so HBM, LDS, VALU, MFMA overlap.
// GATHER: R11's proven pipeline (4-row groups, depth 2, rotated source).

__launch_bounds__(64, 4)
__global__ void fused_mlp_kernel(const float* __restrict__ x,
                                 const int* __restrict__ meta,
                                 const int* __restrict__ idx,
                                 const _Float16* __restrict__ W1F,
                                 const _Float16* __restrict__ W2T,
                                 const float* __restrict__ b1,
                                 const float* __restrict__ b2,
                                 float* __restrict__ out) {
    const int b = blockIdx.x;
    if (b >= meta[12]) return;
    const int t = (b >= meta[9]) + (b >= meta[10]) + (b >= meta[11]);
    const int cnt = meta[t];
    const int row_base = (b - meta[8 + t]) * TBM;
    const int* idx_t = idx + meta[4 + t];

    __shared__ __align__(16) char scratch[8192];   // 2 x 4 KB gather dbuf

    const int lane = threadIdx.x & 63;
    const int l15 = lane & 15;
    const int lg = lane >> 4;

    // preload this wave's 32 row ids (keeps gather vmcnt counting exact)
    int rg[32];
    #pragma unroll
    for (int r = 0; r < 32; ++r)
        rg[r] = idx_t[min(row_base + r, cnt - 1)];
    __builtin_amdgcn_sched_barrier(0);

    // ---- coalesced gather: 32 rows, 8 groups of 4, 2-deep dbuf (R11) ----
    half8 afrag[MT][8];

#define ISSUE_GROUP(G)                                                          \
    {                                                                           \
        _Pragma("unroll")                                                       \
        for (int i = 0; i < 4; ++i) {                                           \
            const char* src = (const char*)(x + (size_t)rg[(G) * 4 + i] * DM)   \
                              + ((lane - i) & 63) * 16;                         \
            __builtin_amdgcn_global_load_lds(                                   \
                (const AS1 void*)src,                                           \
                (AS3 void*)(scratch + ((G) & 1) * 4096 + i * 1024 + lane * 16), \
                16, 0, 0);                                                      \
        }                                                                       \
    }

    ISSUE_GROUP(0)
#define GATHER_GROUP(G)                                                         \
    {                                                                           \
        if ((G) < 7) { __builtin_amdgcn_sched_barrier(0); ISSUE_GROUP((G) + 1) }\
        if ((G) < 7) asm volatile("s_waitcnt vmcnt(4)");                        \
        else         asm volatile("s_waitcnt vmcnt(0)");                        \
        __builtin_amdgcn_sched_barrier(0);                                      \
        if ((l15 >> 2) == ((G) & 3)) {                                          \
            const int r3 = l15 & 3;                                             \
            const char* gb = scratch + ((G) & 1) * 4096 + r3 * 1024;            \
            _Pragma("unroll")                                                   \
            for (int kk = 0; kk < 8; ++kk) {                                    \
                int B0 = kk * 128 + lg * 32;                                    \
                f32x4 v0 = *(const f32x4*)(gb + ((B0 + r3 * 16) & 1023));       \
                f32x4 v1 = *(const f32x4*)(gb + ((B0 + 16 + r3 * 16) & 1023));  \
                half8 h;                                                        \
                h[0] = (_Float16)v0[0]; h[1] = (_Float16)v0[1];                 \
                h[2] = (_Float16)v0[2]; h[3] = (_Float16)v0[3];                 \
                h[4] = (_Float16)v1[0]; h[5] = (_Float16)v1[1];                 \
                h[6] = (_Float16)v1[2]; h[7] = (_Float16)v1[3];                 \
                afrag[(G) >> 2][kk] = h;                                        \
            }                                                                   \
        }                                                                       \
    }

    GATHER_GROUP(0) GATHER_GROUP(1) GATHER_GROUP(2) GATHER_GROUP(3)
    GATHER_GROUP(4) GATHER_GROUP(5) GATHER_GROUP(6) GATHER_GROUP(7)
#undef GATHER_GROUP
#undef ISSUE_GROUP

    const f32x4 fzero = {0.f, 0.f, 0.f, 0.f};
    f32x4 acc2[MT][2];   // out^T frags: lane holds o = nt2*16 + lg*4 + j for row l15
    #pragma unroll
    for (int mt = 0; mt < MT; ++mt)
        #pragma unroll
        for (int nt = 0; nt < 2; ++nt)
            acc2[mt][nt] = fzero;

    const _Float16* w1f = W1F + (size_t)t * HID * DM;   // frag-major
    const _Float16* w2t_t = W2T + (size_t)t * OUTD * HID;
    const float* b1t = b1 + t * HID;

    half8 w2A[2], w2B[2];
    #pragma unroll
    for (int nt = 0; nt < 2; ++nt)
        w2A[nt] = *(const half8*)(w2t_t + (nt * 16 + l15) * HID + lg * 8);

#define CHUNK_BODY(HCI, W2USE, W2FILL)                                          \
    {                                                                           \
        const int hc = (HCI);                                                   \
        {   /* prefetch W2 frags for chunk hc+1 (wrap harmless) */              \
            int hn = (hc + 1) & 15;                                             \
            _Pragma("unroll")                                                   \
            for (int nt = 0; nt < 2; ++nt)                                      \
                W2FILL[nt] = *(const half8*)(w2t_t + (nt * 16 + l15) * HID + hn * HC + lg * 8); \
        }                                                                       \
        f32x4 acc1[MT][2];  /* H^T: lane -> row r=l15, h = nt*16 + lg*4 + j */  \
        _Pragma("unroll")                                                       \
        for (int mt = 0; mt < MT; ++mt)                                         \
            _Pragma("unroll")                                                   \
            for (int nt = 0; nt < 2; ++nt)                                      \
                acc1[mt][nt] = fzero;                                           \
        const _Float16* wchunk = w1f + (size_t)hc * 8192;                       \
        _Pragma("unroll")                                                       \
        for (int kk = 0; kk < 8; ++kk) {                                        \
            half8 bfr[2];                                                       \
            _Pragma("unroll")                                                   \
            for (int nt = 0; nt < 2; ++nt)                                      \
                bfr[nt] = *(const half8*)(wchunk + kk * 1024 + nt * 512 + lane * 8); \
            _Pragma("unroll")                                                   \
            for (int mt = 0; mt < MT; ++mt)                                     \
                _Pragma("unroll")                                               \
                for (int nt = 0; nt < 2; ++nt)                                  \
                    acc1[mt][nt] = __builtin_amdgcn_mfma_f32_16x16x32_f16(      \
                        bfr[nt], afrag[mt][kk], acc1[mt][nt], 0, 0, 0);         \
        }                                                                       \
        /* bias + relu + cvt in regs -> GEMM2 B-frag (pre-permuted W2T) */      \
        {                                                                       \
            f32x4 bv0 = *(const f32x4*)(b1t + hc * HC + lg * 4);                \
            f32x4 bv1 = *(const f32x4*)(b1t + hc * HC + 16 + lg * 4);           \
            _Pragma("unroll")                                                   \
            for (int mt = 0; mt < MT; ++mt) {                                   \
                half8 hfrag;                                                    \
                _Pragma("unroll")                                               \
                for (int j = 0; j < 4; ++j) {                                   \
                    hfrag[j]     = (_Float16)fmaxf(acc1[mt][0][j] + bv0[j], 0.f);\
                    hfrag[4 + j] = (_Float16)fmaxf(acc1[mt][1][j] + bv1[j], 0.f);\
                }                                                               \
                _Pragma("unroll")                                               \
                for (int nt = 0; nt < 2; ++nt)                                  \
                    acc2[mt][nt] = __builtin_amdgcn_mfma_f32_16x16x32_f16(      \
                        W2USE[nt], hfrag, acc2[mt][nt], 0, 0, 0);               \
            }                                                                   \
        }                                                                       \
    }

    #pragma unroll
    for (int h2 = 0; h2 < NCHUNK; h2 += 2) {
        CHUNK_BODY(h2, w2A, w2B);
        CHUNK_BODY(h2 + 1, w2B, w2A);
    }
#undef CHUNK_BODY

    // ---- scatter-store: out^T layout -> per-lane float4 stores ----
    const int m = min(TBM, cnt - row_base);
    f32x4 b2v[2];
    #pragma unroll
    for (int nt = 0; nt < 2; ++nt)
        b2v[nt] = *(const f32x4*)(b2 + t * OUTD + nt * 16 + lg * 4);
    #pragma unroll
    for (int mt = 0; mt < MT; ++mt) {
        int rloc = mt * 16 + l15;
        if (rloc < m) {
            int gr = idx_t[row_base + rloc];
            #pragma unroll
            for (int nt = 0; nt < 2; ++nt) {
                f32x4 v = acc2[mt][nt] + b2v[nt];
                __builtin_nontemporal_store(v, (f32x4*)(out + (size_t)gr * OUTD + nt * 16 + lg * 4));
            }
        }
    }
}

// ---------------- launch ----------------

extern "C" void kernel_launch(void* const* d_in, const int* in_sizes, int n_in,
                              void* d_out, int out_size, void* d_ws, size_t ws_size,
                              hipStream_t stream) {
    const float* x   = (const float*)d_in[0];
    const int* types = (const int*)d_in[1];
    const float* W1  = (const float*)d_in[2];
    const float* b1  = (const float*)d_in[3];
    const float* W2  = (const float*)d_in[4];
    const float* b2  = (const float*)d_in[5];
    float* out = (float*)d_out;

    char* ws = (char*)d_ws;
    int* meta = (int*)ws;                       // counts/offsets/tileoffs (13 ints)
    int* idx = (int*)(ws + 64);                 // N_TOK int32
    _Float16* W1F = (_Float16*)(ws + 64 + 4 * (size_t)N_TOK);
    _Float16* W2T = W1F + (size_t)NTYPE * HID * DM;
    // bc/bb alias the W1F region: used only BEFORE wprep_kernel writes W1F.
    int* bc = (int*)W1F;                        // [4][512]
    int* bb = bc + NTYPE * NBLK;                // [4][512]

    count_kernel<<<NBLK, 256, 0, stream>>>(types, bc);
    scan_blocks_kernel<<<1, 256, 0, stream>>>(bc, bb, meta);
    scatter2_kernel<<<NBLK, 256, 0, stream>>>(types, bb, idx);
    wprep_kernel<<<(NTYPE * HID * DM) / 256, 256, 0, stream>>>(W1, W2, W1F, W2T);

    fused_mlp_kernel<<<GX1D, 64, 0, stream>>>(x, meta, idx, W1F, W2T, b1, b2, out);
}

// Round 17
// 234.066 us; speedup vs baseline: 1.5832x; 1.5832x over previous
//
#include <hip/hip_runtime.h>
#include <hip/hip_bf16.h>
#include <hip/hip_fp16.h>

#define N_TOK 524288
#define DM 256
#define HID 512
#define OUTD 32
#define NTYPE 4
#define BM 128                     // rows per block (mt=2 per wave, 32 rows/wave)
#define MT 2
#define HC 32
#define NCHUNK (HID / HC)          // 16
#define CHUNK_BYTES (HC * DM * 2)  // 16384
#define NBLK 512                   // partition blocks; N_TOK = NBLK * 1024
#define GX1D (N_TOK / BM + NTYPE)  // exact tiles + per-type ceil slack

typedef _Float16 half8 __attribute__((ext_vector_type(8)));
typedef float f32x4 __attribute__((ext_vector_type(4)));

#define AS1 __attribute__((address_space(1)))
#define AS3 __attribute__((address_space(3)))

// ---------------- prep: count (+ fused weight transform) ----------------
// wprep is folded in via grid-stride: its W1/W2 reads are independent of the
// types scan, so the transform hides under the count pass (saves a launch).
// NOTE: bc/bb no longer alias W1T (see launcher) so this fusion is safe.

__global__ void count_wprep_kernel(const int* __restrict__ types, int* __restrict__ bc,
                                   const float* __restrict__ W1, const float* __restrict__ W2,
                                   _Float16* __restrict__ W1T, _Float16* __restrict__ W2T) {
    __shared__ int c[NTYPE];
    int tid = threadIdx.x;
    if (tid < NTYPE) c[tid] = 0;
    __syncthreads();
    int b = blockIdx.x;
    int lane = tid & 63;
    #pragma unroll
    for (int j = 0; j < 4; ++j) {
        int t = types[b * 1024 + j * 256 + tid];
        #pragma unroll
        for (int tt = 0; tt < NTYPE; ++tt) {
            unsigned long long mask = __ballot(t == tt);
            if (lane == 0) atomicAdd(&c[tt], __popcll(mask));
        }
    }
    __syncthreads();
    if (tid < NTYPE) bc[tid * NBLK + b] = c[tid];

    // ---- fused weight transform (grid-stride) ----
    // W1T: per type, 16 chunks of [32 h][256 d] f16, rows XOR-swizzled
    // (byte_in_row = (d*2) ^ ((hr&7)<<4)), stored linearly in global_load_lds
    // write order (inverse-swizzled source + swizzled read).
    for (int i = b * 256 + tid; i < NTYPE * HID * DM; i += NBLK * 256) {
        int t = i / (HID * DM);
        int r = i - t * (HID * DM);
        int byteoff = r * 2;
        int hc = byteoff / CHUNK_BYTES;
        int rem = byteoff - hc * CHUNK_BYTES;
        int hr = rem >> 9;
        int brow = rem & 511;
        int d = (brow ^ ((hr & 7) << 4)) >> 1;
        int h = hc * HC + hr;
        W1T[i] = (_Float16)W1[(t * DM + d) * HID + h];
    }
    // W2T: [t][o][p] f16, hidden dim permuted per 32-chunk so swapped-GEMM1's
    // register layout (h = nt*16+lg*4+j) equals the K=32 B-operand slot order
    // (p = lg*8+j): p -> h1 = j<4 ? lg*4+j : 16+lg*4+(j-4)
    {
        int i = b * 256 + tid;
        if (i < NTYPE * OUTD * HID) {
            int t = i / (OUTD * HID);
            int r = i - t * (OUTD * HID);
            int o = r / HID;
            int pg = r - o * HID;
            int hc = pg >> 5;
            int p = pg & 31;
            int lg = p >> 3, j = p & 7;
            int h1 = (j < 4) ? (lg * 4 + j) : (16 + lg * 4 + (j - 4));
            int h = hc * HC + h1;
            W2T[i] = (_Float16)W2[(t * HID + h) * OUTD + o];
        }
    }
}

// meta: [0..3] counts, [4..7] row offsets, [8..11] tile offsets, [12] total tiles
__global__ void scan_blocks_kernel(const int* __restrict__ bc,
                                   int* __restrict__ bb,
                                   int* __restrict__ meta) {
    __shared__ int totals[NTYPE];
    __shared__ int typeoff[NTYPE];
    int wave = threadIdx.x >> 6, lane = threadIdx.x & 63;
    int excl[NBLK / 64];
    int running = 0;
    #pragma unroll
    for (int it = 0; it < NBLK / 64; ++it) {
        int v = bc[wave * NBLK + it * 64 + lane];
        int s = v;
        #pragma unroll
        for (int d = 1; d < 64; d <<= 1) {
            int u = __shfl_up(s, d);
            if (lane >= d) s += u;
        }
        excl[it] = running + s - v;
        running += __shfl(s, 63);
    }
    if (lane == 0) totals[wave] = running;
    __syncthreads();
    if (threadIdx.x == 0) {
        int off = 0, toff = 0;
        for (int tt = 0; tt < NTYPE; ++tt) {
            typeoff[tt] = off;
            meta[tt] = totals[tt];
            meta[4 + tt] = off;
            meta[8 + tt] = toff;
            off += totals[tt];
            toff += (totals[tt] + BM - 1) / BM;
        }
        meta[12] = toff;
    }
    __syncthreads();
    #pragma unroll
    for (int it = 0; it < NBLK / 64; ++it)
        bb[wave * NBLK + it * 64 + lane] = typeoff[wave] + excl[it];
}

__global__ void scatter2_kernel(const int* __restrict__ types,
                                const int* __restrict__ bb,
                                int* __restrict__ idx) {
    __shared__ int base[NTYPE];
    __shared__ int wcnt[4][NTYPE];
    int b = blockIdx.x;
    int tid = threadIdx.x, wave = tid >> 6, lane = tid & 63;
    if (tid < NTYPE) base[tid] = bb[tid * NBLK + b];
    #pragma unroll
    for (int j = 0; j < 4; ++j) {
        __syncthreads();
        int i = b * 1024 + j * 256 + tid;
        int t = types[i];
        int rank = 0;
        #pragma unroll
        for (int tt = 0; tt < NTYPE; ++tt) {
            unsigned long long mask = __ballot(t == tt);
            if (t == tt) rank = __popcll(mask & ((1ull << lane) - 1ull));
            if (lane == 0) wcnt[wave][tt] = __popcll(mask);
        }
        __syncthreads();
        int pre = 0;
        for (int w = 0; w < wave; ++w) pre += wcnt[w][t];
        idx[base[t] + pre + rank] = i;
        __syncthreads();
        if (tid < NTYPE) {
            int tot = 0;
            #pragma unroll
            for (int w = 0; w < 4; ++w) tot += wcnt[w][tid];
            base[tid] += tot;
        }
    }
}

// ---------------- fused grouped MLP (R11 structure + T5 setprio) ----------
// 256 threads = 4 waves; block = 128 gathered rows of one type (32/wave).
// GATHER: per row one global_load_lds reads the full 1 KB row contiguously
// (per-lane source rotated by ((lane-r)&63)*16), 4-row groups, 2-deep dbuf in
// wave-private scratch aliasing W1sB; redistribute un-rotates via &1023.
// CHUNK LOOP: W1 LDS dbuf DMA'd 1 chunk ahead, W2 reg ping-pong prefetch,
// reg-H via swapped MFMA + permuted W2T, plain __syncthreads per chunk.
// NEW: s_setprio(1) around the MFMA cluster (T5) — co-resident blocks sit at
// different phases (gather vs chunks), so compute-phase waves get priority
// over gather-issuing waves on the same SIMD.

__launch_bounds__(256)
__global__ void fused_mlp_kernel(const float* __restrict__ x,
                                 const int* __restrict__ meta,
                                 const int* __restrict__ idx,
                                 const _Float16* __restrict__ W1T,
                                 const _Float16* __restrict__ W2T,
                                 const float* __restrict__ b1,
                                 const float* __restrict__ b2,
                                 float* __restrict__ out) {
    const int b = blockIdx.x;
    if (b >= meta[12]) return;
    const int t = (b >= meta[9]) + (b >= meta[10]) + (b >= meta[11]);
    const int cnt = meta[t];
    const int row_base = (b - meta[8 + t]) * BM;
    const int* idx_t = idx + meta[4 + t];

    __shared__ __align__(16) char W1sB[2][CHUNK_BYTES];  // 32 KB dbuf (+ gather scratch)
    __shared__ __align__(16) float b1s[HID];             // 2 KB

    const int tid = threadIdx.x;
    const int wave = tid >> 6;
    const int lane = tid & 63;
    const int l15 = lane & 15;
    const int lg = lane >> 4;

    // bias -> LDS (before any gather DMA; its compiler vmcnt wait lands here)
    {
        float2 bv = *(const float2*)(b1 + t * HID + tid * 2);
        b1s[tid * 2] = bv.x;
        b1s[tid * 2 + 1] = bv.y;
    }
    __builtin_amdgcn_sched_barrier(0);

    // preload this wave's 32 row ids (keeps the gather vmcnt count exact)
    int rg[32];
    #pragma unroll
    for (int r = 0; r < 32; ++r)
        rg[r] = idx_t[min(row_base + wave * 32 + r, cnt - 1)];
    __builtin_amdgcn_sched_barrier(0);

    // ---- coalesced gather: 32 rows/wave, 8 groups of 4, 2-deep dbuf ----
    half8 afrag[MT][8];
    char* scratch = &W1sB[0][0] + wave * 8192;   // 2 x 4 KB halves

#define ISSUE_GROUP(G)                                                          \
    {                                                                           \
        _Pragma("unroll")                                                       \
        for (int i = 0; i < 4; ++i) {                                           \
            const char* src = (const char*)(x + (size_t)rg[(G) * 4 + i] * DM)   \
                              + ((lane - i) & 63) * 16;                         \
            __builtin_amdgcn_global_load_lds(                                   \
                (const AS1 void*)src,                                           \
                (AS3 void*)(scratch + ((G) & 1) * 4096 + i * 1024), 16, 0, 0);  \
        }                                                                       \
    }

    ISSUE_GROUP(0)
#define GATHER_GROUP(G)                                                         \
    {                                                                           \
        if ((G) < 7) { __builtin_amdgcn_sched_barrier(0); ISSUE_GROUP((G) + 1) }\
        if ((G) < 7) asm volatile("s_waitcnt vmcnt(4)");                        \
        else         asm volatile("s_waitcnt vmcnt(0)");                        \
        __builtin_amdgcn_sched_barrier(0);                                      \
        if ((l15 >> 2) == ((G) & 3)) {                                          \
            const int r3 = l15 & 3;                                             \
            const char* gb = scratch + ((G) & 1) * 4096 + r3 * 1024;            \
            _Pragma("unroll")                                                   \
            for (int kk = 0; kk < 8; ++kk) {                                    \
                int B0 = kk * 128 + lg * 32;                                    \
                f32x4 v0 = *(const f32x4*)(gb + ((B0 + r3 * 16) & 1023));       \
                f32x4 v1 = *(const f32x4*)(gb + ((B0 + 16 + r3 * 16) & 1023));  \
                half8 h;                                                        \
                h[0] = (_Float16)v0[0]; h[1] = (_Float16)v0[1];                 \
                h[2] = (_Float16)v0[2]; h[3] = (_Float16)v0[3];                 \
                h[4] = (_Float16)v1[0]; h[5] = (_Float16)v1[1];                 \
                h[6] = (_Float16)v1[2]; h[7] = (_Float16)v1[3];                 \
                afrag[(G) >> 2][kk] = h;                                        \
            }                                                                   \
        }                                                                       \
    }

    GATHER_GROUP(0) GATHER_GROUP(1) GATHER_GROUP(2) GATHER_GROUP(3)
    GATHER_GROUP(4) GATHER_GROUP(5) GATHER_GROUP(6) GATHER_GROUP(7)
#undef GATHER_GROUP
#undef ISSUE_GROUP

    __syncthreads();  // all waves done with W1sB-as-scratch

    const f32x4 fzero = {0.f, 0.f, 0.f, 0.f};
    f32x4 acc2[MT][2];   // out^T frags: lane holds o = nt2*16 + lg*4 + j for row l15
    #pragma unroll
    for (int mt = 0; mt < MT; ++mt)
        #pragma unroll
        for (int nt = 0; nt < 2; ++nt)
            acc2[mt][nt] = fzero;

    const char* w1base = (const char*)(W1T + (size_t)t * HID * DM);
    const _Float16* w2t_t = W2T + (size_t)t * OUTD * HID;

    // stage chunk 0 + W2 frags chunk 0
    #pragma unroll
    for (int it = 0; it < 4; ++it) {
        __builtin_amdgcn_global_load_lds(
            (const AS1 void*)(w1base + it * 4096 + tid * 16),
            (AS3 void*)(&W1sB[0][it * 4096 + tid * 16]),
            16, 0, 0);
    }
    half8 w2A[2], w2B[2];
    #pragma unroll
    for (int nt = 0; nt < 2; ++nt)
        w2A[nt] = *(const half8*)(w2t_t + (nt * 16 + l15) * HID + lg * 8);
    __syncthreads();  // chunk0 DMA drained (vmcnt0 at barrier)

#define CHUNK_BODY(HCI, W2USE, W2FILL)                                          \
    {                                                                           \
        const int hc = (HCI);                                                   \
        const char* cur = W1sB[hc & 1];                                         \
        if (hc + 1 < NCHUNK) {                                                  \
            const char* src = w1base + (size_t)(hc + 1) * CHUNK_BYTES;          \
            char* dst = W1sB[(hc + 1) & 1];                                     \
            _Pragma("unroll")                                                   \
            for (int it = 0; it < 4; ++it) {                                    \
                __builtin_amdgcn_global_load_lds(                               \
                    (const AS1 void*)(src + it * 4096 + tid * 16),              \
                    (AS3 void*)(dst + it * 4096 + tid * 16),                    \
                    16, 0, 0);                                                  \
            }                                                                   \
        }                                                                       \
        {   /* prefetch W2 frags for chunk hc+1 (wrap harmless) */              \
            int hn = (hc + 1) & 15;                                             \
            _Pragma("unroll")                                                   \
            for (int nt = 0; nt < 2; ++nt)                                      \
                W2FILL[nt] = *(const half8*)(w2t_t + (nt * 16 + l15) * HID + hn * HC + lg * 8); \
        }                                                                       \
        f32x4 acc1[MT][2];  /* H^T: lane -> row r=l15, h = nt*16 + lg*4 + j */  \
        _Pragma("unroll")                                                       \
        for (int mt = 0; mt < MT; ++mt)                                         \
            _Pragma("unroll")                                                   \
            for (int nt = 0; nt < 2; ++nt)                                      \
                acc1[mt][nt] = fzero;                                           \
        __builtin_amdgcn_s_setprio(1);  /* T5: favor compute-phase waves */     \
        _Pragma("unroll")                                                       \
        for (int kk = 0; kk < 8; ++kk) {                                        \
            half8 bfr[2];                                                       \
            _Pragma("unroll")                                                   \
            for (int nt = 0; nt < 2; ++nt) {                                    \
                int hr = nt * 16 + l15;                                         \
                bfr[nt] = *(const half8*)(cur + hr * 512 +                      \
                            ((kk * 64 + lg * 16) ^ ((hr & 7) << 4)));           \
            }                                                                   \
            _Pragma("unroll")                                                   \
            for (int mt = 0; mt < MT; ++mt)                                     \
                _Pragma("unroll")                                               \
                for (int nt = 0; nt < 2; ++nt)                                  \
                    acc1[mt][nt] = __builtin_amdgcn_mfma_f32_16x16x32_f16(      \
                        bfr[nt], afrag[mt][kk], acc1[mt][nt], 0, 0, 0);         \
        }                                                                       \
        /* bias + relu + cvt in regs -> GEMM2 B-frag (pre-permuted W2T) */      \
        {                                                                       \
            f32x4 bv0 = *(const f32x4*)(b1s + hc * HC + lg * 4);                \
            f32x4 bv1 = *(const f32x4*)(b1s + hc * HC + 16 + lg * 4);           \
            _Pragma("unroll")                                                   \
            for (int mt = 0; mt < MT; ++mt) {                                   \
                half8 hfrag;                                                    \
                _Pragma("unroll")                                               \
                for (int j = 0; j < 4; ++j) {                                   \
                    hfrag[j]     = (_Float16)fmaxf(acc1[mt][0][j] + bv0[j], 0.f);\
                    hfrag[4 + j] = (_Float16)fmaxf(acc1[mt][1][j] + bv1[j], 0.f);\
                }                                                               \
                _Pragma("unroll")                                               \
                for (int nt = 0; nt < 2; ++nt)                                  \
                    acc2[mt][nt] = __builtin_amdgcn_mfma_f32_16x16x32_f16(      \
                        W2USE[nt], hfrag, acc2[mt][nt], 0, 0, 0);               \
            }                                                                   \
        }                                                                       \
        __builtin_amdgcn_s_setprio(0);                                          \
        __syncthreads(); /* drains next-chunk DMA; issued one chunk earlier */  \
    }

    #pragma unroll
    for (int h2 = 0; h2 < NCHUNK; h2 += 2) {
        CHUNK_BODY(h2, w2A, w2B);
        CHUNK_BODY(h2 + 1, w2B, w2A);
    }
#undef CHUNK_BODY

    // ---- scatter-store: out^T layout -> per-lane float4 stores ----
    const int m = min(BM, cnt - row_base);
    f32x4 b2v[2];
    #pragma unroll
    for (int nt = 0; nt < 2; ++nt)
        b2v[nt] = *(const f32x4*)(b2 + t * OUTD + nt * 16 + lg * 4);
    #pragma unroll
    for (int mt = 0; mt < MT; ++mt) {
        int rloc = wave * (MT * 16) + mt * 16 + l15;
        if (rloc < m) {
            int gr = idx_t[row_base + rloc];
            #pragma unroll
            for (int nt = 0; nt < 2; ++nt) {
                f32x4 v = acc2[mt][nt] + b2v[nt];
                __builtin_nontemporal_store(v, (f32x4*)(out + (size_t)gr * OUTD + nt * 16 + lg * 4));
            }
        }
    }
}

// ---------------- launch ----------------

extern "C" void kernel_launch(void* const* d_in, const int* in_sizes, int n_in,
                              void* d_out, int out_size, void* d_ws, size_t ws_size,
                              hipStream_t stream) {
    const float* x   = (const float*)d_in[0];
    const int* types = (const int*)d_in[1];
    const float* W1  = (const float*)d_in[2];
    const float* b1  = (const float*)d_in[3];
    const float* W2  = (const float*)d_in[4];
    const float* b2  = (const float*)d_in[5];
    float* out = (float*)d_out;

    char* ws = (char*)d_ws;
    int* meta = (int*)ws;                       // counts/offsets/tileoffs (13 ints)
    int* idx = (int*)(ws + 64);                 // N_TOK int32
    _Float16* W1T = (_Float16*)(ws + 64 + 4 * (size_t)N_TOK);
    _Float16* W2T = W1T + (size_t)NTYPE * HID * DM;
    // bc/bb live AFTER the weight buffers now (no aliasing) so the weight
    // transform can be fused into count_kernel.
    int* bc = (int*)(W2T + (size_t)NTYPE * OUTD * HID);   // [4][512]
    int* bb = bc + NTYPE * NBLK;                          // [4][512]

    count_wprep_kernel<<<NBLK, 256, 0, stream>>>(types, bc, W1, W2, W1T, W2T);
    scan_blocks_kernel<<<1, 256, 0, stream>>>(bc, bb, meta);
    scatter2_kernel<<<NBLK, 256, 0, stream>>>(types, bb, idx);

    fused_mlp_kernel<<<GX1D, 256, 0, stream>>>(x, meta, idx, W1T, W2T, b1, b2, out);
}

// Round 18
// 232.070 us; speedup vs baseline: 1.5968x; 1.0086x over previous
//
#include <hip/hip_runtime.h>
#include <hip/hip_bf16.h>
#include <hip/hip_fp16.h>

#define N_TOK 524288
#define DM 256
#define HID 512
#define OUTD 32
#define NTYPE 4
#define BM 128                     // rows per block (mt=2 per wave, 32 rows/wave)
#define MT 2
#define HC 32
#define NCHUNK (HID / HC)          // 16
#define CHUNK_BYTES (HC * DM * 2)  // 16384
#define NBLK 512                   // partition blocks; N_TOK = NBLK * 1024
#define GX1D (N_TOK / BM + NTYPE)  // exact tiles + per-type ceil slack

typedef _Float16 half8 __attribute__((ext_vector_type(8)));
typedef float f32x4 __attribute__((ext_vector_type(4)));

#define AS1 __attribute__((address_space(1)))
#define AS3 __attribute__((address_space(3)))

// ---------------- prep: count (+ fused weight transform) ----------------

__global__ void count_wprep_kernel(const int* __restrict__ types, int* __restrict__ bc,
                                   const float* __restrict__ W1, const float* __restrict__ W2,
                                   _Float16* __restrict__ W1T, _Float16* __restrict__ W2T) {
    __shared__ int c[NTYPE];
    int tid = threadIdx.x;
    if (tid < NTYPE) c[tid] = 0;
    __syncthreads();
    int b = blockIdx.x;
    int lane = tid & 63;
    #pragma unroll
    for (int j = 0; j < 4; ++j) {
        int t = types[b * 1024 + j * 256 + tid];
        #pragma unroll
        for (int tt = 0; tt < NTYPE; ++tt) {
            unsigned long long mask = __ballot(t == tt);
            if (lane == 0) atomicAdd(&c[tt], __popcll(mask));
        }
    }
    __syncthreads();
    if (tid < NTYPE) bc[tid * NBLK + b] = c[tid];

    // ---- fused weight transform (grid-stride) ----
    // W1T: per type, 16 chunks of [32 h][256 d] f16, rows XOR-swizzled
    // (byte_in_row = (d*2) ^ ((hr&7)<<4)), stored linearly in global_load_lds
    // write order (inverse-swizzled source + swizzled read).
    for (int i = b * 256 + tid; i < NTYPE * HID * DM; i += NBLK * 256) {
        int t = i / (HID * DM);
        int r = i - t * (HID * DM);
        int byteoff = r * 2;
        int hc = byteoff / CHUNK_BYTES;
        int rem = byteoff - hc * CHUNK_BYTES;
        int hr = rem >> 9;
        int brow = rem & 511;
        int d = (brow ^ ((hr & 7) << 4)) >> 1;
        int h = hc * HC + hr;
        W1T[i] = (_Float16)W1[(t * DM + d) * HID + h];
    }
    // W2T: [t][o][p] f16, hidden dim permuted per 32-chunk so swapped-GEMM1's
    // register layout (h = nt*16+lg*4+j) equals the K=32 B-operand slot order
    // (p = lg*8+j): p -> h1 = j<4 ? lg*4+j : 16+lg*4+(j-4)
    {
        int i = b * 256 + tid;
        if (i < NTYPE * OUTD * HID) {
            int t = i / (OUTD * HID);
            int r = i - t * (OUTD * HID);
            int o = r / HID;
            int pg = r - o * HID;
            int hc = pg >> 5;
            int p = pg & 31;
            int lg = p >> 3, j = p & 7;
            int h1 = (j < 4) ? (lg * 4 + j) : (16 + lg * 4 + (j - 4));
            int h = hc * HC + h1;
            W2T[i] = (_Float16)W2[(t * HID + h) * OUTD + o];
        }
    }
}

// ---------------- merged scan + scatter ----------------
// Each block redundantly computes its own per-type base from bc (8 KB of L2
// reads, wave-parallel: wave t reduces type t's 512 counts, masking i < b for
// the prefix). Removes the separate 1-block scan launch from the serial prep
// chain. Block 0 additionally writes meta for the fused kernel.

__global__ void scan_scatter_kernel(const int* __restrict__ types,
                                    const int* __restrict__ bc,
                                    int* __restrict__ idx,
                                    int* __restrict__ meta) {
    __shared__ int pre[NTYPE];    // prefix of own type up to block b
    __shared__ int tot[NTYPE];    // type totals
    __shared__ int base[NTYPE];
    __shared__ int wcnt[4][NTYPE];
    const int b = blockIdx.x;
    const int tid = threadIdx.x, wave = tid >> 6, lane = tid & 63;

    // wave t: total + prefix(i<b) of bc[t][*]
    {
        int v1 = 0, v2 = 0;
        #pragma unroll
        for (int it = 0; it < NBLK / 64; ++it) {
            int i = it * 64 + lane;
            int v = bc[wave * NBLK + i];
            v2 += v;
            if (i < b) v1 += v;
        }
        #pragma unroll
        for (int d = 32; d >= 1; d >>= 1) {
            v1 += __shfl_down(v1, d);
            v2 += __shfl_down(v2, d);
        }
        if (lane == 0) { pre[wave] = v1; tot[wave] = v2; }
    }
    __syncthreads();
    if (tid == 0) {
        int off = 0, toff = 0;
        #pragma unroll
        for (int tt = 0; tt < NTYPE; ++tt) {
            base[tt] = off + pre[tt];
            if (b == 0) {
                meta[tt] = tot[tt];
                meta[4 + tt] = off;
                meta[8 + tt] = toff;
            }
            off += tot[tt];
            toff += (tot[tt] + BM - 1) / BM;
        }
        if (b == 0) meta[12] = toff;
    }

    #pragma unroll
    for (int j = 0; j < 4; ++j) {
        __syncthreads();
        int i = b * 1024 + j * 256 + tid;
        int t = types[i];
        int rank = 0;
        #pragma unroll
        for (int tt = 0; tt < NTYPE; ++tt) {
            unsigned long long mask = __ballot(t == tt);
            if (t == tt) rank = __popcll(mask & ((1ull << lane) - 1ull));
            if (lane == 0) wcnt[wave][tt] = __popcll(mask);
        }
        __syncthreads();
        int pre2 = 0;
        for (int w = 0; w < wave; ++w) pre2 += wcnt[w][t];
        idx[base[t] + pre2 + rank] = i;
        __syncthreads();
        if (tid < NTYPE) {
            int s = 0;
            #pragma unroll
            for (int w = 0; w < 4; ++w) s += wcnt[w][tid];
            base[tid] += s;
        }
    }
}

// ---------------- fused grouped MLP (R11 structure + T5 setprio) ----------
// 256 threads = 4 waves; block = 128 gathered rows of one type (32/wave).
// GATHER: per row one global_load_lds reads the full 1 KB row contiguously
// (per-lane source rotated by ((lane-r)&63)*16), 4-row groups, 2-deep dbuf in
// wave-private scratch aliasing W1sB; redistribute un-rotates via &1023.
// CHUNK LOOP: W1 LDS dbuf DMA'd 1 chunk ahead, W2 reg ping-pong prefetch,
// reg-H via swapped MFMA + permuted W2T, plain __syncthreads per chunk.

__launch_bounds__(256)
__global__ void fused_mlp_kernel(const float* __restrict__ x,
                                 const int* __restrict__ meta,
                                 const int* __restrict__ idx,
                                 const _Float16* __restrict__ W1T,
                                 const _Float16* __restrict__ W2T,
                                 const float* __restrict__ b1,
                                 const float* __restrict__ b2,
                                 float* __restrict__ out) {
    const int b = blockIdx.x;
    if (b >= meta[12]) return;
    const int t = (b >= meta[9]) + (b >= meta[10]) + (b >= meta[11]);
    const int cnt = meta[t];
    const int row_base = (b - meta[8 + t]) * BM;
    const int* idx_t = idx + meta[4 + t];

    __shared__ __align__(16) char W1sB[2][CHUNK_BYTES];  // 32 KB dbuf (+ gather scratch)
    __shared__ __align__(16) float b1s[HID];             // 2 KB

    const int tid = threadIdx.x;
    const int wave = tid >> 6;
    const int lane = tid & 63;
    const int l15 = lane & 15;
    const int lg = lane >> 4;

    // bias -> LDS (before any gather DMA; its compiler vmcnt wait lands here)
    {
        float2 bv = *(const float2*)(b1 + t * HID + tid * 2);
        b1s[tid * 2] = bv.x;
        b1s[tid * 2 + 1] = bv.y;
    }
    __builtin_amdgcn_sched_barrier(0);

    // preload this wave's 32 row ids (keeps the gather vmcnt count exact)
    int rg[32];
    #pragma unroll
    for (int r = 0; r < 32; ++r)
        rg[r] = idx_t[min(row_base + wave * 32 + r, cnt - 1)];
    __builtin_amdgcn_sched_barrier(0);

    // ---- coalesced gather: 32 rows/wave, 8 groups of 4, 2-deep dbuf ----
    half8 afrag[MT][8];
    char* scratch = &W1sB[0][0] + wave * 8192;   // 2 x 4 KB halves

#define ISSUE_GROUP(G)                                                          \
    {                                                                           \
        _Pragma("unroll")                                                       \
        for (int i = 0; i < 4; ++i) {                                           \
            const char* src = (const char*)(x + (size_t)rg[(G) * 4 + i] * DM)   \
                              + ((lane - i) & 63) * 16;                         \
            __builtin_amdgcn_global_load_lds(                                   \
                (const AS1 void*)src,                                           \
                (AS3 void*)(scratch + ((G) & 1) * 4096 + i * 1024), 16, 0, 0);  \
        }                                                                       \
    }

    ISSUE_GROUP(0)
#define GATHER_GROUP(G)                                                         \
    {                                                                           \
        if ((G) < 7) { __builtin_amdgcn_sched_barrier(0); ISSUE_GROUP((G) + 1) }\
        if ((G) < 7) asm volatile("s_waitcnt vmcnt(4)");                        \
        else         asm volatile("s_waitcnt vmcnt(0)");                        \
        __builtin_amdgcn_sched_barrier(0);                                      \
        if ((l15 >> 2) == ((G) & 3)) {                                          \
            const int r3 = l15 & 3;                                             \
            const char* gb = scratch + ((G) & 1) * 4096 + r3 * 1024;            \
            _Pragma("unroll")                                                   \
            for (int kk = 0; kk < 8; ++kk) {                                    \
                int B0 = kk * 128 + lg * 32;                                    \
                f32x4 v0 = *(const f32x4*)(gb + ((B0 + r3 * 16) & 1023));       \
                f32x4 v1 = *(const f32x4*)(gb + ((B0 + 16 + r3 * 16) & 1023));  \
                half8 h;                                                        \
                h[0] = (_Float16)v0[0]; h[1] = (_Float16)v0[1];                 \
                h[2] = (_Float16)v0[2]; h[3] = (_Float16)v0[3];                 \
                h[4] = (_Float16)v1[0]; h[5] = (_Float16)v1[1];                 \
                h[6] = (_Float16)v1[2]; h[7] = (_Float16)v1[3];                 \
                afrag[(G) >> 2][kk] = h;                                        \
            }                                                                   \
        }                                                                       \
    }

    GATHER_GROUP(0) GATHER_GROUP(1) GATHER_GROUP(2) GATHER_GROUP(3)
    GATHER_GROUP(4) GATHER_GROUP(5) GATHER_GROUP(6) GATHER_GROUP(7)
#undef GATHER_GROUP
#undef ISSUE_GROUP

    __syncthreads();  // all waves done with W1sB-as-scratch

    const f32x4 fzero = {0.f, 0.f, 0.f, 0.f};
    f32x4 acc2[MT][2];   // out^T frags: lane holds o = nt2*16 + lg*4 + j for row l15
    #pragma unroll
    for (int mt = 0; mt < MT; ++mt)
        #pragma unroll
        for (int nt = 0; nt < 2; ++nt)
            acc2[mt][nt] = fzero;

    const char* w1base = (const char*)(W1T + (size_t)t * HID * DM);
    const _Float16* w2t_t = W2T + (size_t)t * OUTD * HID;

    // stage chunk 0 + W2 frags chunk 0
    #pragma unroll
    for (int it = 0; it < 4; ++it) {
        __builtin_amdgcn_global_load_lds(
            (const AS1 void*)(w1base + it * 4096 + tid * 16),
            (AS3 void*)(&W1sB[0][it * 4096 + tid * 16]),
            16, 0, 0);
    }
    half8 w2A[2], w2B[2];
    #pragma unroll
    for (int nt = 0; nt < 2; ++nt)
        w2A[nt] = *(const half8*)(w2t_t + (nt * 16 + l15) * HID + lg * 8);
    __syncthreads();  // chunk0 DMA drained (vmcnt0 at barrier)

#define CHUNK_BODY(HCI, W2USE, W2FILL)                                          \
    {                                                                           \
        const int hc = (HCI);                                                   \
        const char* cur = W1sB[hc & 1];                                         \
        if (hc + 1 < NCHUNK) {                                                  \
            const char* src = w1base + (size_t)(hc + 1) * CHUNK_BYTES;          \
            char* dst = W1sB[(hc + 1) & 1];                                     \
            _Pragma("unroll")                                                   \
            for (int it = 0; it < 4; ++it) {                                    \
                __builtin_amdgcn_global_load_lds(                               \
                    (const AS1 void*)(src + it * 4096 + tid * 16),              \
                    (AS3 void*)(dst + it * 4096 + tid * 16),                    \
                    16, 0, 0);                                                  \
            }                                                                   \
        }                                                                       \
        {   /* prefetch W2 frags for chunk hc+1 (wrap harmless) */              \
            int hn = (hc + 1) & 15;                                             \
            _Pragma("unroll")                                                   \
            for (int nt = 0; nt < 2; ++nt)                                      \
                W2FILL[nt] = *(const half8*)(w2t_t + (nt * 16 + l15) * HID + hn * HC + lg * 8); \
        }                                                                       \
        f32x4 acc1[MT][2];  /* H^T: lane -> row r=l15, h = nt*16 + lg*4 + j */  \
        _Pragma("unroll")                                                       \
        for (int mt = 0; mt < MT; ++mt)                                         \
            _Pragma("unroll")                                                   \
            for (int nt = 0; nt < 2; ++nt)                                      \
                acc1[mt][nt] = fzero;                                           \
        __builtin_amdgcn_s_setprio(1);  /* T5: favor compute-phase waves */     \
        _Pragma("unroll")                                                       \
        for (int kk = 0; kk < 8; ++kk) {                                        \
            half8 bfr[2];                                                       \
            _Pragma("unroll")                                                   \
            for (int nt = 0; nt < 2; ++nt) {                                    \
                int hr = nt * 16 + l15;                                         \
                bfr[nt] = *(const half8*)(cur + hr * 512 +                      \
                            ((kk * 64 + lg * 16) ^ ((hr & 7) << 4)));           \
            }                                                                   \
            _Pragma("unroll")                                                   \
            for (int mt = 0; mt < MT; ++mt)                                     \
                _Pragma("unroll")                                               \
                for (int nt = 0; nt < 2; ++nt)                                  \
                    acc1[mt][nt] = __builtin_amdgcn_mfma_f32_16x16x32_f16(      \
                        bfr[nt], afrag[mt][kk], acc1[mt][nt], 0, 0, 0);         \
        }                                                                       \
        /* bias + relu + cvt in regs -> GEMM2 B-frag (pre-permuted W2T) */      \
        {                                                                       \
            f32x4 bv0 = *(const f32x4*)(b1s + hc * HC + lg * 4);                \
            f32x4 bv1 = *(const f32x4*)(b1s + hc * HC + 16 + lg * 4);           \
            _Pragma("unroll")                                                   \
            for (int mt = 0; mt < MT; ++mt) {                                   \
                half8 hfrag;                                                    \
                _Pragma("unroll")                                               \
                for (int j = 0; j < 4; ++j) {                                   \
                    hfrag[j]     = (_Float16)fmaxf(acc1[mt][0][j] + bv0[j], 0.f);\
                    hfrag[4 + j] = (_Float16)fmaxf(acc1[mt][1][j] + bv1[j], 0.f);\
                }                                                               \
                _Pragma("unroll")                                               \
                for (int nt = 0; nt < 2; ++nt)                                  \
                    acc2[mt][nt] = __builtin_amdgcn_mfma_f32_16x16x32_f16(      \
                        W2USE[nt], hfrag, acc2[mt][nt], 0, 0, 0);               \
            }                                                                   \
        }                                                                       \
        __builtin_amdgcn_s_setprio(0);                                          \
        __syncthreads(); /* drains next-chunk DMA; issued one chunk earlier */  \
    }

    #pragma unroll
    for (int h2 = 0; h2 < NCHUNK; h2 += 2) {
        CHUNK_BODY(h2, w2A, w2B);
        CHUNK_BODY(h2 + 1, w2B, w2A);
    }
#undef CHUNK_BODY

    // ---- scatter-store: out^T layout -> per-lane float4 stores ----
    const int m = min(BM, cnt - row_base);
    f32x4 b2v[2];
    #pragma unroll
    for (int nt = 0; nt < 2; ++nt)
        b2v[nt] = *(const f32x4*)(b2 + t * OUTD + nt * 16 + lg * 4);
    #pragma unroll
    for (int mt = 0; mt < MT; ++mt) {
        int rloc = wave * (MT * 16) + mt * 16 + l15;
        if (rloc < m) {
            int gr = idx_t[row_base + rloc];
            #pragma unroll
            for (int nt = 0; nt < 2; ++nt) {
                f32x4 v = acc2[mt][nt] + b2v[nt];
                __builtin_nontemporal_store(v, (f32x4*)(out + (size_t)gr * OUTD + nt * 16 + lg * 4));
            }
        }
    }
}

// ---------------- launch ----------------

extern "C" void kernel_launch(void* const* d_in, const int* in_sizes, int n_in,
                              void* d_out, int out_size, void* d_ws, size_t ws_size,
                              hipStream_t stream) {
    const float* x   = (const float*)d_in[0];
    const int* types = (const int*)d_in[1];
    const float* W1  = (const float*)d_in[2];
    const float* b1  = (const float*)d_in[3];
    const float* W2  = (const float*)d_in[4];
    const float* b2  = (const float*)d_in[5];
    float* out = (float*)d_out;

    char* ws = (char*)d_ws;
    int* meta = (int*)ws;                       // counts/offsets/tileoffs (13 ints)
    int* idx = (int*)(ws + 64);                 // N_TOK int32
    _Float16* W1T = (_Float16*)(ws + 64 + 4 * (size_t)N_TOK);
    _Float16* W2T = W1T + (size_t)NTYPE * HID * DM;
    int* bc = (int*)(W2T + (size_t)NTYPE * OUTD * HID);   // [4][512] (no aliasing)

    count_wprep_kernel<<<NBLK, 256, 0, stream>>>(types, bc, W1, W2, W1T, W2T);
    scan_scatter_kernel<<<NBLK, 256, 0, stream>>>(types, bc, idx, meta);

    fused_mlp_kernel<<<GX1D, 256, 0, stream>>>(x, meta, idx, W1T, W2T, b1, b2, out);
}